// Round 5
// baseline (410.788 us; speedup 1.0000x reference)
//
#include <hip/hip_runtime.h>
#include <math.h>

#define DDIM 64
#define BUCKET 1024             // nodes per bucket (binning runs long; fused_cp 1 blk/bucket)
#define LRSHIFT 17              // br-packed: col [0,17), lrow [17,27), val [32,64)
#define CMASK 0x1FFFF
#define LRMASK 0x3FF
#define NBLK 512
#define TPB_BIN 1024
#define NWV 16                  // waves per binning block
#define MAXNB 128               // max buckets (NB = ceil(100000/1024) = 98)

typedef unsigned long long ull;
typedef _Float16 half2_t __attribute__((ext_vector_type(2)));

__device__ inline unsigned int bf16_hi(float v) {       // RNE bf16 bits in high 16
    unsigned int a = __float_as_uint(v);
    return (a + 0x7fffu + ((a >> 16) & 1u)) & 0xffff0000u;
}

__device__ inline unsigned int pk_f16x2(float lo, float hi) {
    return __builtin_bit_cast(unsigned int, __builtin_amdgcn_cvt_pkrtz(lo, hi));
}

__device__ inline half2_t dup_lo16(unsigned int s) {    // (s&0xFFFF) in both halves
    return __builtin_bit_cast(half2_t, __builtin_amdgcn_perm(0u, s, 0x01000100u));
}

__device__ inline half2_t h2_shfl_xor(half2_t v, int off) {
    return __builtin_bit_cast(half2_t, __shfl_xor(__builtin_bit_cast(unsigned int, v), off));
}

// ---- init global fill counters (cacheline-padded: stride 16 ints) ----
__global__ void init_fill_kernel(int* __restrict__ gfill_r, int* __restrict__ gfill_c,
                                 int NB, int cap) {
    int k = blockIdx.x * blockDim.x + threadIdx.x;
    if (k < NB) {
        gfill_r[k * 16] = k * cap;
        gfill_c[k * 16] = k * cap;
    }
}

// ---- fused binning: per-wave count, block reserve, REGISTER-CACHED place ----
// BUCKET=1024: per-(block,bucket) output runs ~64 edges -> full-cacheline writes.
__global__ __launch_bounds__(TPB_BIN)
void binning_kernel(const int* __restrict__ erow, const int* __restrict__ ecol,
                    const float* __restrict__ evals,
                    int* __restrict__ gfill_r, int* __restrict__ gfill_c,
                    ull* __restrict__ br, unsigned int* __restrict__ bc,
                    int E, int NB, int chunk) {
    __shared__ int hr[NWV][MAXNB];
    __shared__ int hc[NWV][MAXNB];
    __shared__ int fr[MAXNB];     // block-level fill cursors (row key)
    __shared__ int fc[MAXNB];     // block-level fill cursors (col key)
    int t = threadIdx.x;
    int wv = t >> 6;
    for (int k = t; k < NWV * MAXNB; k += TPB_BIN) { (&hr[0][0])[k] = 0; (&hc[0][0])[k] = 0; }
    __syncthreads();
    int lo = blockIdx.x * chunk;             // chunk multiple of 4 -> lo 16B-aligned
    int hi = min(E, lo + chunk);
    int nq = (hi - lo) >> 2;
    int rem = (hi - lo) & 3;
    // phase 1: per-wave count; cache edge data in registers (chunk <= 8*TPB -> <=2 iters)
    int p0 = t, p1 = t + TPB_BIN;
    bool h0 = p0 < nq, h1 = p1 < nq;
    int4 r40, c40, r41, c41;
    float4 v40, v41;
    if (h0) {
        int i = lo + 4 * p0;
        r40 = *(const int4*)(erow + i);
        c40 = *(const int4*)(ecol + i);
        v40 = *(const float4*)(evals + i);
        atomicAdd(&hr[wv][r40.x >> 10], 1);
        atomicAdd(&hr[wv][r40.y >> 10], 1);
        atomicAdd(&hr[wv][r40.z >> 10], 1);
        atomicAdd(&hr[wv][r40.w >> 10], 1);
        atomicAdd(&hc[wv][c40.x >> 10], 1);
        atomicAdd(&hc[wv][c40.y >> 10], 1);
        atomicAdd(&hc[wv][c40.z >> 10], 1);
        atomicAdd(&hc[wv][c40.w >> 10], 1);
    }
    if (h1) {
        int i = lo + 4 * p1;
        r41 = *(const int4*)(erow + i);
        c41 = *(const int4*)(ecol + i);
        v41 = *(const float4*)(evals + i);
        atomicAdd(&hr[wv][r41.x >> 10], 1);
        atomicAdd(&hr[wv][r41.y >> 10], 1);
        atomicAdd(&hr[wv][r41.z >> 10], 1);
        atomicAdd(&hr[wv][r41.w >> 10], 1);
        atomicAdd(&hc[wv][c41.x >> 10], 1);
        atomicAdd(&hc[wv][c41.y >> 10], 1);
        atomicAdd(&hc[wv][c41.z >> 10], 1);
        atomicAdd(&hc[wv][c41.w >> 10], 1);
    }
    if (t == 0) {
        for (int i = hi - rem; i < hi; i++) {
            atomicAdd(&hr[0][erow[i] >> 10], 1);
            atomicAdd(&hc[0][ecol[i] >> 10], 1);
        }
    }
    __syncthreads();
    // phase 2: ONE reservation per (block,bucket) -> long contiguous output runs
    if (t < NB) {
        int sr = 0, sc = 0;
        #pragma unroll
        for (int w2 = 0; w2 < NWV; w2++) { sr += hr[w2][t]; sc += hc[w2][t]; }
        fr[t] = atomicAdd(&gfill_r[t * 16], sr);
        fc[t] = atomicAdd(&gfill_c[t * 16], sc);
    }
    __syncthreads();
    // phase 3: place from registers (no global re-read)
    if (h0) {
        int pos0 = atomicAdd(&fr[r40.x >> 10], 1);
        int pos1 = atomicAdd(&fr[r40.y >> 10], 1);
        int pos2 = atomicAdd(&fr[r40.z >> 10], 1);
        int pos3 = atomicAdd(&fr[r40.w >> 10], 1);
        br[pos0] = ((ull)__float_as_uint(v40.x) << 32) | ((ull)(r40.x & 1023) << LRSHIFT) | (unsigned)c40.x;
        br[pos1] = ((ull)__float_as_uint(v40.y) << 32) | ((ull)(r40.y & 1023) << LRSHIFT) | (unsigned)c40.y;
        br[pos2] = ((ull)__float_as_uint(v40.z) << 32) | ((ull)(r40.z & 1023) << LRSHIFT) | (unsigned)c40.z;
        br[pos3] = ((ull)__float_as_uint(v40.w) << 32) | ((ull)(r40.w & 1023) << LRSHIFT) | (unsigned)c40.w;
        int q0 = atomicAdd(&fc[c40.x >> 10], 1);
        int q1 = atomicAdd(&fc[c40.y >> 10], 1);
        int q2 = atomicAdd(&fc[c40.z >> 10], 1);
        int q3 = atomicAdd(&fc[c40.w >> 10], 1);
        bc[q0] = bf16_hi(v40.x) | (unsigned)(c40.x & 1023);
        bc[q1] = bf16_hi(v40.y) | (unsigned)(c40.y & 1023);
        bc[q2] = bf16_hi(v40.z) | (unsigned)(c40.z & 1023);
        bc[q3] = bf16_hi(v40.w) | (unsigned)(c40.w & 1023);
    }
    if (h1) {
        int pos0 = atomicAdd(&fr[r41.x >> 10], 1);
        int pos1 = atomicAdd(&fr[r41.y >> 10], 1);
        int pos2 = atomicAdd(&fr[r41.z >> 10], 1);
        int pos3 = atomicAdd(&fr[r41.w >> 10], 1);
        br[pos0] = ((ull)__float_as_uint(v41.x) << 32) | ((ull)(r41.x & 1023) << LRSHIFT) | (unsigned)c41.x;
        br[pos1] = ((ull)__float_as_uint(v41.y) << 32) | ((ull)(r41.y & 1023) << LRSHIFT) | (unsigned)c41.y;
        br[pos2] = ((ull)__float_as_uint(v41.z) << 32) | ((ull)(r41.z & 1023) << LRSHIFT) | (unsigned)c41.z;
        br[pos3] = ((ull)__float_as_uint(v41.w) << 32) | ((ull)(r41.w & 1023) << LRSHIFT) | (unsigned)c41.w;
        int q0 = atomicAdd(&fc[c41.x >> 10], 1);
        int q1 = atomicAdd(&fc[c41.y >> 10], 1);
        int q2 = atomicAdd(&fc[c41.z >> 10], 1);
        int q3 = atomicAdd(&fc[c41.w >> 10], 1);
        bc[q0] = bf16_hi(v41.x) | (unsigned)(c41.x & 1023);
        bc[q1] = bf16_hi(v41.y) | (unsigned)(c41.y & 1023);
        bc[q2] = bf16_hi(v41.z) | (unsigned)(c41.z & 1023);
        bc[q3] = bf16_hi(v41.w) | (unsigned)(c41.w & 1023);
    }
    if (t == 0) {
        for (int i = hi - rem; i < hi; i++) {
            int r = erow[i], c = ecol[i];
            float v = evals[i];
            int pos = atomicAdd(&fr[r >> 10], 1);
            br[pos] = ((ull)__float_as_uint(v) << 32) | ((ull)(r & 1023) << LRSHIFT) | (unsigned)c;
            int pos2 = atomicAdd(&fc[c >> 10], 1);
            bc[pos2] = bf16_hi(v) | (unsigned)(c & 1023);
        }
    }
}

// ---- fused count+scan+place: ONE 1024-thread block per 1024-node bucket ----
// cw weight = v * inv_r[row] only.  inv_c is applied to the FEATURES (cvt pre-scales
// layer 0; spmm epilogue scales its output row) and cancels in the loss's L2-normalize.
// 16 waves/block hide the L2 latency; place pass re-reads the L2-hot br slice.
__global__ __launch_bounds__(BUCKET)
void fused_cp_kernel(const ull* __restrict__ br, const unsigned int* __restrict__ bc,
                     const int* __restrict__ gfill_r, const int* __restrict__ gfill_c,
                     int2* __restrict__ rse, float* __restrict__ inv_c,
                     unsigned int* __restrict__ cw, int N, int cap) {
    __shared__ int   cnt[BUCKET];     // counts, then reused as placement cursors
    __shared__ float ds[BUCKET];      // row degree sums
    __shared__ float dsc[BUCKET];     // col degree sums
    __shared__ int   sc[BUCKET];      // scan workspace
    __shared__ float invr[BUCKET];
    int b = blockIdx.x, t = threadIdx.x;
    cnt[t] = 0; ds[t] = 0.0f; dsc[t] = 0.0f;
    __syncthreads();
    int s = b * cap;
    int e = gfill_r[b * 16];
    int m = s + ((e - s) & ~3);
    for (int i = s + 4 * t; i < m; i += 4 * BUCKET) {
        ull p0 = br[i];
        ull p1 = br[i + 1];
        ull p2 = br[i + 2];
        ull p3 = br[i + 3];
        int lr0 = (int)((p0 >> LRSHIFT) & LRMASK);
        int lr1 = (int)((p1 >> LRSHIFT) & LRMASK);
        int lr2 = (int)((p2 >> LRSHIFT) & LRMASK);
        int lr3 = (int)((p3 >> LRSHIFT) & LRMASK);
        atomicAdd(&cnt[lr0], 1);
        atomicAdd(&cnt[lr1], 1);
        atomicAdd(&cnt[lr2], 1);
        atomicAdd(&cnt[lr3], 1);
        atomicAdd(&ds[lr0], __uint_as_float((unsigned)(p0 >> 32)));
        atomicAdd(&ds[lr1], __uint_as_float((unsigned)(p1 >> 32)));
        atomicAdd(&ds[lr2], __uint_as_float((unsigned)(p2 >> 32)));
        atomicAdd(&ds[lr3], __uint_as_float((unsigned)(p3 >> 32)));
    }
    if (t == 0) {
        for (int i = m; i < e; i++) {
            ull p = br[i];
            int lr = (int)((p >> LRSHIFT) & LRMASK);
            atomicAdd(&cnt[lr], 1);
            atomicAdd(&ds[lr], __uint_as_float((unsigned)(p >> 32)));
        }
    }
    int e2 = gfill_c[b * 16];
    int m2 = s + ((e2 - s) & ~3);
    for (int i = s + 4 * t; i < m2; i += 4 * BUCKET) {
        uint4 p = *(const uint4*)(bc + i);
        atomicAdd(&dsc[p.x & 0x3FFu], __uint_as_float(p.x & 0xffff0000u));
        atomicAdd(&dsc[p.y & 0x3FFu], __uint_as_float(p.y & 0xffff0000u));
        atomicAdd(&dsc[p.z & 0x3FFu], __uint_as_float(p.z & 0xffff0000u));
        atomicAdd(&dsc[p.w & 0x3FFu], __uint_as_float(p.w & 0xffff0000u));
    }
    if (t == 0) {
        for (int i = m2; i < e2; i++) {
            unsigned int p = bc[i];
            atomicAdd(&dsc[p & 0x3FFu], __uint_as_float(p & 0xffff0000u));
        }
    }
    __syncthreads();
    // scan of mod-4-rounded counts (row starts 16B-aligned for uint4 cw quads)
    int c0 = cnt[t];
    int sum4 = (c0 + 3) & ~3;
    sc[t] = sum4;
    __syncthreads();
    for (int off = 1; off < BUCKET; off <<= 1) {
        int v = (t >= off) ? sc[t - off] : 0;
        __syncthreads();
        sc[t] += v;
        __syncthreads();
    }
    int st = s + sc[t] - sum4;
    int node = b * BUCKET + t;
    if (node < N) {
        int2 se;
        se.x = st;
        se.y = st + c0;
        rse[node] = se;
    }
    inv_c[node] = 1.0f / (sqrtf(dsc[t]) + 1e-8f);   // padded nodes never referenced
    invr[t] = 1.0f / (sqrtf(ds[t]) + 1e-8f);
    __syncthreads();                                // all reads of cnt[] done before reuse
    cnt[t] = st;                                    // reuse as cursor
    __syncthreads();
    // place pass (br slice is L2-hot from the count pass)
    for (int i = s + 4 * t; i < m; i += 4 * BUCKET) {
        ull p0 = br[i];
        ull p1 = br[i + 1];
        ull p2 = br[i + 2];
        ull p3 = br[i + 3];
        int c0_ = (int)(p0 & CMASK), c1_ = (int)(p1 & CMASK);
        int c2_ = (int)(p2 & CMASK), c3_ = (int)(p3 & CMASK);
        int lr0 = (int)((p0 >> LRSHIFT) & LRMASK);
        int lr1 = (int)((p1 >> LRSHIFT) & LRMASK);
        int lr2 = (int)((p2 >> LRSHIFT) & LRMASK);
        int lr3 = (int)((p3 >> LRSHIFT) & LRMASK);
        float v0 = __uint_as_float((unsigned)(p0 >> 32));
        float v1 = __uint_as_float((unsigned)(p1 >> 32));
        float v2 = __uint_as_float((unsigned)(p2 >> 32));
        float v3 = __uint_as_float((unsigned)(p3 >> 32));
        int pos0 = atomicAdd(&cnt[lr0], 1);
        int pos1 = atomicAdd(&cnt[lr1], 1);
        int pos2 = atomicAdd(&cnt[lr2], 1);
        int pos3 = atomicAdd(&cnt[lr3], 1);
        float w0 = v0 * invr[lr0];
        float w1 = v1 * invr[lr1];
        float w2 = v2 * invr[lr2];
        float w3 = v3 * invr[lr3];
        cw[pos0] = ((unsigned)c0_ << 15) | ((pk_f16x2(w0, w0) & 0xFFFFu) >> 1);
        cw[pos1] = ((unsigned)c1_ << 15) | ((pk_f16x2(w1, w1) & 0xFFFFu) >> 1);
        cw[pos2] = ((unsigned)c2_ << 15) | ((pk_f16x2(w2, w2) & 0xFFFFu) >> 1);
        cw[pos3] = ((unsigned)c3_ << 15) | ((pk_f16x2(w3, w3) & 0xFFFFu) >> 1);
    }
    if (t == 0) {
        for (int i = m; i < e; i++) {
            ull p = br[i];
            int c = (int)(p & CMASK);
            int lr = (int)((p >> LRSHIFT) & LRMASK);
            float v = __uint_as_float((unsigned)(p >> 32));
            int pos = atomicAdd(&cnt[lr], 1);
            float wv = v * invr[lr];
            cw[pos] = ((unsigned)c << 15) | ((pk_f16x2(wv, wv) & 0xFFFFu) >> 1);
        }
    }
}

// ---- cvt: fb0 = f16(inv_c * nf); 4 floats/thread ----
__global__ void cvt_kernel(const float* __restrict__ src, const float* __restrict__ inv_c,
                           unsigned int* __restrict__ dst, long n4) {
    long i = (long)blockIdx.x * blockDim.x + threadIdx.x;
    if (i < n4) {
        float ic = inv_c[i >> 4];           // 16 threads per 64-float row
        float4 v = ((const float4*)src)[i];
        uint2 o;
        o.x = pk_f16x2(v.x * ic, v.y * ic);
        o.y = pk_f16x2(v.z * ic, v.w * ic);
        ((uint2*)dst)[i] = o;
    }
}

// ---- SpMM: wave per row, 32 edges/iter via uint4 cw quads, batched gathers ----
// fin carries inv_c scale; epilogue multiplies the output row by inv_c[wid] so the
// next layer's gather is correctly scaled. Row-uniform scale cancels in loss norm.
__global__ __launch_bounds__(256)
void spmm_f16_kernel(const int2* __restrict__ rse,
                     const unsigned int* __restrict__ cw,
                     const float* __restrict__ inv_c,
                     const unsigned short* __restrict__ fin,
                     unsigned short* __restrict__ fout, int N) {
    int wid = blockIdx.x * (blockDim.x >> 6) + (threadIdx.x >> 6);   // row
    if (wid >= N) return;
    int lane = threadIdx.x & 63;
    int g = lane >> 3;          // edge-quad slot 0..7 (32 edges per iteration)
    int h = lane & 7;           // feature chunk (8 f16 = 16 B)
    int2 se = rse[wid];
    float ic = inv_c[wid];
    int s = se.x, e = se.y;     // s multiple of 4 -> uint4-aligned cw quads
    half2_t a2[8];
    #pragma unroll
    for (int k = 0; k < 8; k++) a2[k] = (half2_t)0;

    for (int base = s; base < e; base += 32) {
        int j = base + 4 * g;
        if (j < e) {
            uint4 pw = *(const uint4*)(cw + j);
            int c0 = (int)(pw.x >> 15);
            int c1 = (j + 1 < e) ? (int)(pw.y >> 15) : c0;
            int c2 = (j + 2 < e) ? (int)(pw.z >> 15) : c0;
            int c3 = (j + 3 < e) ? (int)(pw.w >> 15) : c0;
            uint4 q0 = ((const uint4*)(fin + ((long)c0 << 6)))[h];
            uint4 q1 = ((const uint4*)(fin + ((long)c1 << 6)))[h];
            uint4 q2 = ((const uint4*)(fin + ((long)c2 << 6)))[h];
            uint4 q3 = ((const uint4*)(fin + ((long)c3 << 6)))[h];
            half2_t w0 = dup_lo16(pw.x << 1);
            half2_t w1 = (j + 1 < e) ? dup_lo16(pw.y << 1) : (half2_t)0;
            half2_t w2 = (j + 2 < e) ? dup_lo16(pw.z << 1) : (half2_t)0;
            half2_t w3 = (j + 3 < e) ? dup_lo16(pw.w << 1) : (half2_t)0;
            a2[0] += w0 * __builtin_bit_cast(half2_t, q0.x);
            a2[1] += w0 * __builtin_bit_cast(half2_t, q0.y);
            a2[2] += w0 * __builtin_bit_cast(half2_t, q0.z);
            a2[3] += w0 * __builtin_bit_cast(half2_t, q0.w);
            a2[4] += w1 * __builtin_bit_cast(half2_t, q1.x);
            a2[5] += w1 * __builtin_bit_cast(half2_t, q1.y);
            a2[6] += w1 * __builtin_bit_cast(half2_t, q1.z);
            a2[7] += w1 * __builtin_bit_cast(half2_t, q1.w);
            a2[0] += w2 * __builtin_bit_cast(half2_t, q2.x);
            a2[1] += w2 * __builtin_bit_cast(half2_t, q2.y);
            a2[2] += w2 * __builtin_bit_cast(half2_t, q2.z);
            a2[3] += w2 * __builtin_bit_cast(half2_t, q2.w);
            a2[4] += w3 * __builtin_bit_cast(half2_t, q3.x);
            a2[5] += w3 * __builtin_bit_cast(half2_t, q3.y);
            a2[6] += w3 * __builtin_bit_cast(half2_t, q3.z);
            a2[7] += w3 * __builtin_bit_cast(half2_t, q3.w);
        }
    }

    // reduce slot partials across lane groups; lanes g==0 scale by inv_c and write
    #pragma unroll
    for (int k = 0; k < 4; k++) a2[k] += a2[k + 4];
    #pragma unroll
    for (int k = 0; k < 4; k++) {
        a2[k] += h2_shfl_xor(a2[k], 8);
        a2[k] += h2_shfl_xor(a2[k], 16);
        a2[k] += h2_shfl_xor(a2[k], 32);
    }
    if (g == 0) {
        half2_t ich = __builtin_bit_cast(half2_t, pk_f16x2(ic, ic));
        uint4 o;
        o.x = __builtin_bit_cast(unsigned int, a2[0] * ich);
        o.y = __builtin_bit_cast(unsigned int, a2[1] * ich);
        o.z = __builtin_bit_cast(unsigned int, a2[2] * ich);
        o.w = __builtin_bit_cast(unsigned int, a2[3] * ich);
        ((uint4*)(fout + ((long)wid << 6)))[h] = o;
    }
}

// ---- loss: reconstruct rep rows on the fly (f32 norms, layer-0 from f32 nf) ----
// stored_l = inv_c * x_l (row-uniform positive scale) -> x_l/||x_l|| == stored/||stored||
__device__ inline float rep_at(const float* __restrict__ nf,
                               const unsigned short* __restrict__ f1,
                               const unsigned short* __restrict__ f2,
                               const unsigned short* __restrict__ f3,
                               int id, int lane) {
    long off = (long)id * DDIM + lane;
    float r  = nf[off];
    float v1 = (float)__builtin_bit_cast(_Float16, f1[off]);
    float v2 = (float)__builtin_bit_cast(_Float16, f2[off]);
    float v3 = (float)__builtin_bit_cast(_Float16, f3[off]);
    float s1 = v1 * v1, s2 = v2 * v2, s3 = v3 * v3;
    #pragma unroll
    for (int o = 1; o < 64; o <<= 1) {
        s1 += __shfl_xor(s1, o);
        s2 += __shfl_xor(s2, o);
        s3 += __shfl_xor(s3, o);
    }
    r += v1 / fmaxf(sqrtf(s1), 1e-12f);
    r += v2 / fmaxf(sqrtf(s2), 1e-12f);
    r += v3 / fmaxf(sqrtf(s3), 1e-12f);
    return r;
}

__global__ void loss_terms_kernel(const float* __restrict__ nf,
                                  const unsigned short* __restrict__ f1,
                                  const unsigned short* __restrict__ f2,
                                  const unsigned short* __restrict__ f3,
                                  const int* __restrict__ a_id, const int* __restrict__ p_id,
                                  const int* __restrict__ n_id,
                                  float* __restrict__ terms, int B) {
    long gid = (long)blockIdx.x * blockDim.x + threadIdx.x;
    int b = (int)(gid >> 6);
    int lane = threadIdx.x & 63;
    if (b < B) {
        float ra = rep_at(nf, f1, f2, f3, a_id[b], lane);
        float rp = rep_at(nf, f1, f2, f3, p_id[b], lane);
        float rn = rep_at(nf, f1, f2, f3, n_id[b], lane);
        float dp = ra * rp, dn = ra * rn;
        #pragma unroll
        for (int off = 1; off < 64; off <<= 1) { dp += __shfl_xor(dp, off); dn += __shfl_xor(dn, off); }
        if (lane == 0) {
            float x = (dp - dn) * 0.0625f;   // node_rep = rep/4 -> preds scale 1/16
            terms[b] = fmaxf(-x, 0.0f) + log1pf(expf(-fabsf(x)));
        }
    }
}

__global__ void reduce_kernel(const float* __restrict__ terms, float* __restrict__ out, int B) {
    __shared__ float sm[256];
    float s = 0.0f;
    for (int i = threadIdx.x; i < B; i += 256) s += terms[i];
    sm[threadIdx.x] = s;
    __syncthreads();
    for (int stride = 128; stride > 0; stride >>= 1) {
        if (threadIdx.x < stride) sm[threadIdx.x] += sm[threadIdx.x + stride];
        __syncthreads();
    }
    if (threadIdx.x == 0) out[0] = sm[0] / (float)B;
}

extern "C" void kernel_launch(void* const* d_in, const int* in_sizes, int n_in,
                              void* d_out, int out_size, void* d_ws, size_t ws_size,
                              hipStream_t stream) {
    const float* nf    = (const float*)d_in[0];
    const int*   erow  = (const int*)d_in[1];
    const int*   ecol  = (const int*)d_in[2];
    const float* evals = (const float*)d_in[3];
    const int*   a_id  = (const int*)d_in[4];
    const int*   p_id  = (const int*)d_in[5];
    const int*   n_id  = (const int*)d_in[6];

    int N = in_sizes[0] / DDIM;
    int E = in_sizes[1];
    int B = in_sizes[4];
    int NB = (N + BUCKET - 1) / BUCKET;
    int chunk = (((E + NBLK - 1) / NBLK) + 3) & ~3;   // multiple of 4 -> aligned quad loads
    int Npad = NB * BUCKET;

    // bucket capacity: mean + ~8.3% (15 sigma) + 5120 (mod-4 rounding pad 3072 + guard)
    long capl = ((long)E * BUCKET) / N;
    int cap = (int)(capl + capl / 12 + 5120);
    cap = (cap + 63) & ~63;

    size_t regionA = (size_t)cap * NB * 8;            // br (8 B), later fb0+fb1
    size_t regionB = (size_t)cap * NB * 4;            // bc (4 B), later cw (4 B)
    size_t featB16 = (size_t)N * DDIM * 2;
    if (regionA < 2 * featB16) regionA = 2 * featB16;

    char* w = (char*)d_ws;
    ull*  br     = (ull*)w;
    char* regAp  = w;                 w += regionA;
    unsigned int* bc = (unsigned int*)w;
    unsigned int* cw = (unsigned int*)w;  w += regionB + 256;  // +256: spmm quad tail overread pad
    unsigned short* fb2 = (unsigned short*)w;  w += featB16;   // layer-2 output
    float* inv_c = (float*)w;         w += (size_t)Npad * 4;
    int2* rse    = (int2*)w;          w += (size_t)N * 8;
    int* gfill_r = (int*)w;           w += (size_t)NB * 16 * 4;
    int* gfill_c = (int*)w;           w += (size_t)NB * 16 * 4;
    float* terms = (float*)w;         w += (size_t)B * 4;

    unsigned short* fb0 = (unsigned short*)regAp;             // aliases br (dead after fused_cp)
    unsigned short* fb1 = (unsigned short*)(regAp + featB16);

    init_fill_kernel<<<1, 128, 0, stream>>>(gfill_r, gfill_c, NB, cap);
    binning_kernel<<<NBLK, TPB_BIN, 0, stream>>>(erow, ecol, evals, gfill_r, gfill_c,
                                                 br, bc, E, NB, chunk);
    fused_cp_kernel<<<NB, BUCKET, 0, stream>>>(br, bc, gfill_r, gfill_c,
                                               rse, inv_c, cw, N, cap);

    long n4 = (long)N * DDIM / 4;
    cvt_kernel<<<(unsigned)((n4 + 255) / 256), 256, 0, stream>>>(nf, inv_c, (unsigned int*)fb0, n4);

    unsigned spmmGrid = (unsigned)((N + 3) / 4);   // 4 waves (rows) per 256-thread block
    // layers: fb0 -> fb1 -> fb2 -> fb0 (fb0 slot reused; loss reads f32 nf for layer 0)
    spmm_f16_kernel<<<spmmGrid, 256, 0, stream>>>(rse, cw, inv_c, fb0, fb1, N);
    spmm_f16_kernel<<<spmmGrid, 256, 0, stream>>>(rse, cw, inv_c, fb1, fb2, N);
    spmm_f16_kernel<<<spmmGrid, 256, 0, stream>>>(rse, cw, inv_c, fb2, fb0, N);

    loss_terms_kernel<<<(unsigned)(((long)B * 64 + 255) / 256), 256, 0, stream>>>(
        nf, fb1, fb2, fb0, a_id, p_id, n_id, terms, B);
    reduce_kernel<<<1, 256, 0, stream>>>(terms, (float*)d_out, B);
}

// Round 6
// 358.287 us; speedup vs baseline: 1.1465x; 1.1465x over previous
//
#include <hip/hip_runtime.h>
#include <math.h>

#define DDIM 64
#define BUCKET 1024             // nodes per binning bucket (long runs -> coalesced binning)
#define SUBB 256                // nodes per fused_cp sub-bucket (4 sub-blocks per bucket)
#define LRSHIFT 17              // br-packed: col [0,17), lrow [17,27), val [32,64)
#define CMASK 0x1FFFF
#define LRMASK 0x3FF
#define NBLK 512
#define TPB_BIN 1024
#define NWV 16                  // waves per binning block
#define MAXNB 128               // max buckets (NB = ceil(100000/1024) = 98)

typedef unsigned long long ull;
typedef _Float16 half2_t __attribute__((ext_vector_type(2)));

__device__ inline unsigned int bf16_hi(float v) {       // RNE bf16 bits in high 16
    unsigned int a = __float_as_uint(v);
    return (a + 0x7fffu + ((a >> 16) & 1u)) & 0xffff0000u;
}

__device__ inline unsigned int pk_f16x2(float lo, float hi) {
    return __builtin_bit_cast(unsigned int, __builtin_amdgcn_cvt_pkrtz(lo, hi));
}

__device__ inline half2_t dup_lo16(unsigned int s) {    // (s&0xFFFF) in both halves
    return __builtin_bit_cast(half2_t, __builtin_amdgcn_perm(0u, s, 0x01000100u));
}

__device__ inline half2_t h2_shfl_xor(half2_t v, int off) {
    return __builtin_bit_cast(half2_t, __shfl_xor(__builtin_bit_cast(unsigned int, v), off));
}

// ---- init global fill counters (cacheline-padded: stride 16 ints) ----
__global__ void init_fill_kernel(int* __restrict__ gfill_r, int* __restrict__ gfill_c,
                                 int NB, int cap) {
    int k = blockIdx.x * blockDim.x + threadIdx.x;
    if (k < NB) {
        gfill_r[k * 16] = k * cap;
        gfill_c[k * 16] = k * cap;
    }
}

// ---- fused binning: per-wave count, block reserve, REGISTER-CACHED place ----
// BUCKET=1024: per-(block,bucket) output runs ~64 edges -> full-cacheline writes.
__global__ __launch_bounds__(TPB_BIN)
void binning_kernel(const int* __restrict__ erow, const int* __restrict__ ecol,
                    const float* __restrict__ evals,
                    int* __restrict__ gfill_r, int* __restrict__ gfill_c,
                    ull* __restrict__ br, unsigned int* __restrict__ bc,
                    int E, int NB, int chunk) {
    __shared__ int hr[NWV][MAXNB];
    __shared__ int hc[NWV][MAXNB];
    __shared__ int fr[MAXNB];     // block-level fill cursors (row key)
    __shared__ int fc[MAXNB];     // block-level fill cursors (col key)
    int t = threadIdx.x;
    int wv = t >> 6;
    for (int k = t; k < NWV * MAXNB; k += TPB_BIN) { (&hr[0][0])[k] = 0; (&hc[0][0])[k] = 0; }
    __syncthreads();
    int lo = blockIdx.x * chunk;             // chunk multiple of 4 -> lo 16B-aligned
    int hi = min(E, lo + chunk);
    int nq = (hi - lo) >> 2;
    int rem = (hi - lo) & 3;
    // phase 1: per-wave count; cache edge data in registers (chunk <= 8*TPB -> <=2 iters)
    int p0 = t, p1 = t + TPB_BIN;
    bool h0 = p0 < nq, h1 = p1 < nq;
    int4 r40, c40, r41, c41;
    float4 v40, v41;
    if (h0) {
        int i = lo + 4 * p0;
        r40 = *(const int4*)(erow + i);
        c40 = *(const int4*)(ecol + i);
        v40 = *(const float4*)(evals + i);
        atomicAdd(&hr[wv][r40.x >> 10], 1);
        atomicAdd(&hr[wv][r40.y >> 10], 1);
        atomicAdd(&hr[wv][r40.z >> 10], 1);
        atomicAdd(&hr[wv][r40.w >> 10], 1);
        atomicAdd(&hc[wv][c40.x >> 10], 1);
        atomicAdd(&hc[wv][c40.y >> 10], 1);
        atomicAdd(&hc[wv][c40.z >> 10], 1);
        atomicAdd(&hc[wv][c40.w >> 10], 1);
    }
    if (h1) {
        int i = lo + 4 * p1;
        r41 = *(const int4*)(erow + i);
        c41 = *(const int4*)(ecol + i);
        v41 = *(const float4*)(evals + i);
        atomicAdd(&hr[wv][r41.x >> 10], 1);
        atomicAdd(&hr[wv][r41.y >> 10], 1);
        atomicAdd(&hr[wv][r41.z >> 10], 1);
        atomicAdd(&hr[wv][r41.w >> 10], 1);
        atomicAdd(&hc[wv][c41.x >> 10], 1);
        atomicAdd(&hc[wv][c41.y >> 10], 1);
        atomicAdd(&hc[wv][c41.z >> 10], 1);
        atomicAdd(&hc[wv][c41.w >> 10], 1);
    }
    if (t == 0) {
        for (int i = hi - rem; i < hi; i++) {
            atomicAdd(&hr[0][erow[i] >> 10], 1);
            atomicAdd(&hc[0][ecol[i] >> 10], 1);
        }
    }
    __syncthreads();
    // phase 2: ONE reservation per (block,bucket) -> long contiguous output runs
    if (t < NB) {
        int sr = 0, sc = 0;
        #pragma unroll
        for (int w2 = 0; w2 < NWV; w2++) { sr += hr[w2][t]; sc += hc[w2][t]; }
        fr[t] = atomicAdd(&gfill_r[t * 16], sr);
        fc[t] = atomicAdd(&gfill_c[t * 16], sc);
    }
    __syncthreads();
    // phase 3: place from registers (no global re-read)
    if (h0) {
        int pos0 = atomicAdd(&fr[r40.x >> 10], 1);
        int pos1 = atomicAdd(&fr[r40.y >> 10], 1);
        int pos2 = atomicAdd(&fr[r40.z >> 10], 1);
        int pos3 = atomicAdd(&fr[r40.w >> 10], 1);
        br[pos0] = ((ull)__float_as_uint(v40.x) << 32) | ((ull)(r40.x & 1023) << LRSHIFT) | (unsigned)c40.x;
        br[pos1] = ((ull)__float_as_uint(v40.y) << 32) | ((ull)(r40.y & 1023) << LRSHIFT) | (unsigned)c40.y;
        br[pos2] = ((ull)__float_as_uint(v40.z) << 32) | ((ull)(r40.z & 1023) << LRSHIFT) | (unsigned)c40.z;
        br[pos3] = ((ull)__float_as_uint(v40.w) << 32) | ((ull)(r40.w & 1023) << LRSHIFT) | (unsigned)c40.w;
        int q0 = atomicAdd(&fc[c40.x >> 10], 1);
        int q1 = atomicAdd(&fc[c40.y >> 10], 1);
        int q2 = atomicAdd(&fc[c40.z >> 10], 1);
        int q3 = atomicAdd(&fc[c40.w >> 10], 1);
        bc[q0] = bf16_hi(v40.x) | (unsigned)(c40.x & 1023);
        bc[q1] = bf16_hi(v40.y) | (unsigned)(c40.y & 1023);
        bc[q2] = bf16_hi(v40.z) | (unsigned)(c40.z & 1023);
        bc[q3] = bf16_hi(v40.w) | (unsigned)(c40.w & 1023);
    }
    if (h1) {
        int pos0 = atomicAdd(&fr[r41.x >> 10], 1);
        int pos1 = atomicAdd(&fr[r41.y >> 10], 1);
        int pos2 = atomicAdd(&fr[r41.z >> 10], 1);
        int pos3 = atomicAdd(&fr[r41.w >> 10], 1);
        br[pos0] = ((ull)__float_as_uint(v41.x) << 32) | ((ull)(r41.x & 1023) << LRSHIFT) | (unsigned)c41.x;
        br[pos1] = ((ull)__float_as_uint(v41.y) << 32) | ((ull)(r41.y & 1023) << LRSHIFT) | (unsigned)c41.y;
        br[pos2] = ((ull)__float_as_uint(v41.z) << 32) | ((ull)(r41.z & 1023) << LRSHIFT) | (unsigned)c41.z;
        br[pos3] = ((ull)__float_as_uint(v41.w) << 32) | ((ull)(r41.w & 1023) << LRSHIFT) | (unsigned)c41.w;
        int q0 = atomicAdd(&fc[c41.x >> 10], 1);
        int q1 = atomicAdd(&fc[c41.y >> 10], 1);
        int q2 = atomicAdd(&fc[c41.z >> 10], 1);
        int q3 = atomicAdd(&fc[c41.w >> 10], 1);
        bc[q0] = bf16_hi(v41.x) | (unsigned)(c41.x & 1023);
        bc[q1] = bf16_hi(v41.y) | (unsigned)(c41.y & 1023);
        bc[q2] = bf16_hi(v41.z) | (unsigned)(c41.z & 1023);
        bc[q3] = bf16_hi(v41.w) | (unsigned)(c41.w & 1023);
    }
    if (t == 0) {
        for (int i = hi - rem; i < hi; i++) {
            int r = erow[i], c = ecol[i];
            float v = evals[i];
            int pos = atomicAdd(&fr[r >> 10], 1);
            br[pos] = ((ull)__float_as_uint(v) << 32) | ((ull)(r & 1023) << LRSHIFT) | (unsigned)c;
            int pos2 = atomicAdd(&fc[c >> 10], 1);
            bc[pos2] = bf16_hi(v) | (unsigned)(c & 1023);
        }
    }
}

// ---- fused count+scan+place, SUB-BUCKET version: 4 blocks per 1024-node bucket ----
// Block (b,q): counts the WHOLE bucket-b slice (needed for the 1024-wide scan, which
// each sub-block computes redundantly -- no cross-block communication; the slice is
// L2-hot and shared by the 4 concurrent sub-blocks), but OWNS only quarter q:
// ds/dsc/invr/inv_c/cursors/placement are filtered to lr>>8==q.
// cw weight = v * inv_r[row] only; inv_c is carried by the features (cvt / spmm
// epilogue) and cancels in the loss's L2-normalize.
__global__ __launch_bounds__(1024)
void fused_cp_kernel(const ull* __restrict__ br, const unsigned int* __restrict__ bc,
                     const int* __restrict__ gfill_r, const int* __restrict__ gfill_c,
                     int2* __restrict__ rse, float* __restrict__ inv_c,
                     unsigned int* __restrict__ cw, int N, int cap) {
    __shared__ int   cnt[BUCKET];     // full-bucket counts (for the scan)
    __shared__ int   sc[BUCKET];      // scan workspace
    __shared__ float ds[SUBB];        // row degree sums, quarter only
    __shared__ float dsc[SUBB];       // col degree sums, quarter only
    __shared__ float invr[SUBB];
    __shared__ int   cur[SUBB];       // placement cursors, quarter only
    int b = blockIdx.x >> 2, q = blockIdx.x & 3;
    int t = threadIdx.x;
    cnt[t] = 0;
    if (t < SUBB) { ds[t] = 0.0f; dsc[t] = 0.0f; }
    __syncthreads();
    int s = b * cap;
    int e = gfill_r[b * 16];
    int m = s + ((e - s) & ~3);
    // count pass: cnt for all 1024 nodes; ds only for owned quarter
    for (int i = s + 4 * t; i < m; i += 4 * BUCKET) {
        ull p0 = br[i];
        ull p1 = br[i + 1];
        ull p2 = br[i + 2];
        ull p3 = br[i + 3];
        int lr0 = (int)((p0 >> LRSHIFT) & LRMASK);
        int lr1 = (int)((p1 >> LRSHIFT) & LRMASK);
        int lr2 = (int)((p2 >> LRSHIFT) & LRMASK);
        int lr3 = (int)((p3 >> LRSHIFT) & LRMASK);
        atomicAdd(&cnt[lr0], 1);
        atomicAdd(&cnt[lr1], 1);
        atomicAdd(&cnt[lr2], 1);
        atomicAdd(&cnt[lr3], 1);
        if ((lr0 >> 8) == q) atomicAdd(&ds[lr0 & 255], __uint_as_float((unsigned)(p0 >> 32)));
        if ((lr1 >> 8) == q) atomicAdd(&ds[lr1 & 255], __uint_as_float((unsigned)(p1 >> 32)));
        if ((lr2 >> 8) == q) atomicAdd(&ds[lr2 & 255], __uint_as_float((unsigned)(p2 >> 32)));
        if ((lr3 >> 8) == q) atomicAdd(&ds[lr3 & 255], __uint_as_float((unsigned)(p3 >> 32)));
    }
    if (t == 0) {
        for (int i = m; i < e; i++) {
            ull p = br[i];
            int lr = (int)((p >> LRSHIFT) & LRMASK);
            atomicAdd(&cnt[lr], 1);
            if ((lr >> 8) == q) atomicAdd(&ds[lr & 255], __uint_as_float((unsigned)(p >> 32)));
        }
    }
    // col-degree pass: dsc only for owned quarter
    int e2 = gfill_c[b * 16];
    int m2 = s + ((e2 - s) & ~3);
    for (int i = s + 4 * t; i < m2; i += 4 * BUCKET) {
        uint4 p = *(const uint4*)(bc + i);
        int lc0 = (int)(p.x & 0x3FFu);
        int lc1 = (int)(p.y & 0x3FFu);
        int lc2 = (int)(p.z & 0x3FFu);
        int lc3 = (int)(p.w & 0x3FFu);
        if ((lc0 >> 8) == q) atomicAdd(&dsc[lc0 & 255], __uint_as_float(p.x & 0xffff0000u));
        if ((lc1 >> 8) == q) atomicAdd(&dsc[lc1 & 255], __uint_as_float(p.y & 0xffff0000u));
        if ((lc2 >> 8) == q) atomicAdd(&dsc[lc2 & 255], __uint_as_float(p.z & 0xffff0000u));
        if ((lc3 >> 8) == q) atomicAdd(&dsc[lc3 & 255], __uint_as_float(p.w & 0xffff0000u));
    }
    if (t == 0) {
        for (int i = m2; i < e2; i++) {
            unsigned int p = bc[i];
            int lc = (int)(p & 0x3FFu);
            if ((lc >> 8) == q) atomicAdd(&dsc[lc & 255], __uint_as_float(p & 0xffff0000u));
        }
    }
    __syncthreads();
    // full-bucket scan of mod-4-rounded counts (row starts 16B-aligned cw quads)
    int c0v = cnt[t];
    int sum4 = (c0v + 3) & ~3;
    sc[t] = sum4;
    __syncthreads();
    for (int off = 1; off < BUCKET; off <<= 1) {
        int v = (t >= off) ? sc[t - off] : 0;
        __syncthreads();
        sc[t] += v;
        __syncthreads();
    }
    int st = s + sc[t] - sum4;
    if ((t >> 8) == q) {                 // quarter owner writes outputs + cursors
        int node = b * BUCKET + t;
        if (node < N) {
            int2 se;
            se.x = st;
            se.y = st + c0v;
            rse[node] = se;
        }
        inv_c[node] = 1.0f / (sqrtf(dsc[t & 255]) + 1e-8f);   // pad nodes unreferenced
        invr[t & 255] = 1.0f / (sqrtf(ds[t & 255]) + 1e-8f);
        cur[t & 255] = st;
    }
    __syncthreads();
    // place pass: full slice scan (L2-hot), place only owned-quarter edges
    for (int i = s + 4 * t; i < m; i += 4 * BUCKET) {
        ull p0 = br[i];
        ull p1 = br[i + 1];
        ull p2 = br[i + 2];
        ull p3 = br[i + 3];
        int lr0 = (int)((p0 >> LRSHIFT) & LRMASK);
        int lr1 = (int)((p1 >> LRSHIFT) & LRMASK);
        int lr2 = (int)((p2 >> LRSHIFT) & LRMASK);
        int lr3 = (int)((p3 >> LRSHIFT) & LRMASK);
        if ((lr0 >> 8) == q) {
            int pos = atomicAdd(&cur[lr0 & 255], 1);
            float wv = __uint_as_float((unsigned)(p0 >> 32)) * invr[lr0 & 255];
            cw[pos] = ((unsigned)(p0 & CMASK) << 15) | ((pk_f16x2(wv, wv) & 0xFFFFu) >> 1);
        }
        if ((lr1 >> 8) == q) {
            int pos = atomicAdd(&cur[lr1 & 255], 1);
            float wv = __uint_as_float((unsigned)(p1 >> 32)) * invr[lr1 & 255];
            cw[pos] = ((unsigned)(p1 & CMASK) << 15) | ((pk_f16x2(wv, wv) & 0xFFFFu) >> 1);
        }
        if ((lr2 >> 8) == q) {
            int pos = atomicAdd(&cur[lr2 & 255], 1);
            float wv = __uint_as_float((unsigned)(p2 >> 32)) * invr[lr2 & 255];
            cw[pos] = ((unsigned)(p2 & CMASK) << 15) | ((pk_f16x2(wv, wv) & 0xFFFFu) >> 1);
        }
        if ((lr3 >> 8) == q) {
            int pos = atomicAdd(&cur[lr3 & 255], 1);
            float wv = __uint_as_float((unsigned)(p3 >> 32)) * invr[lr3 & 255];
            cw[pos] = ((unsigned)(p3 & CMASK) << 15) | ((pk_f16x2(wv, wv) & 0xFFFFu) >> 1);
        }
    }
    if (t == 0) {
        for (int i = m; i < e; i++) {
            ull p = br[i];
            int lr = (int)((p >> LRSHIFT) & LRMASK);
            if ((lr >> 8) == q) {
                int pos = atomicAdd(&cur[lr & 255], 1);
                float wv = __uint_as_float((unsigned)(p >> 32)) * invr[lr & 255];
                cw[pos] = ((unsigned)(p & CMASK) << 15) | ((pk_f16x2(wv, wv) & 0xFFFFu) >> 1);
            }
        }
    }
}

// ---- cvt: fb0 = f16(inv_c * nf); 4 floats/thread ----
__global__ void cvt_kernel(const float* __restrict__ src, const float* __restrict__ inv_c,
                           unsigned int* __restrict__ dst, long n4) {
    long i = (long)blockIdx.x * blockDim.x + threadIdx.x;
    if (i < n4) {
        float ic = inv_c[i >> 4];           // 16 threads per 64-float row
        float4 v = ((const float4*)src)[i];
        uint2 o;
        o.x = pk_f16x2(v.x * ic, v.y * ic);
        o.y = pk_f16x2(v.z * ic, v.w * ic);
        ((uint2*)dst)[i] = o;
    }
}

// ---- SpMM: wave per row, 32 edges/iter via uint4 cw quads, batched gathers ----
// fin carries inv_c scale; epilogue multiplies the output row by inv_c[wid] so the
// next layer's gather is correctly scaled. Row-uniform scale cancels in loss norm.
__global__ __launch_bounds__(256)
void spmm_f16_kernel(const int2* __restrict__ rse,
                     const unsigned int* __restrict__ cw,
                     const float* __restrict__ inv_c,
                     const unsigned short* __restrict__ fin,
                     unsigned short* __restrict__ fout, int N) {
    int wid = blockIdx.x * (blockDim.x >> 6) + (threadIdx.x >> 6);   // row
    if (wid >= N) return;
    int lane = threadIdx.x & 63;
    int g = lane >> 3;          // edge-quad slot 0..7 (32 edges per iteration)
    int h = lane & 7;           // feature chunk (8 f16 = 16 B)
    int2 se = rse[wid];
    float ic = inv_c[wid];
    int s = se.x, e = se.y;     // s multiple of 4 -> uint4-aligned cw quads
    half2_t a2[8];
    #pragma unroll
    for (int k = 0; k < 8; k++) a2[k] = (half2_t)0;

    for (int base = s; base < e; base += 32) {
        int j = base + 4 * g;
        if (j < e) {
            uint4 pw = *(const uint4*)(cw + j);
            int c0 = (int)(pw.x >> 15);
            int c1 = (j + 1 < e) ? (int)(pw.y >> 15) : c0;
            int c2 = (j + 2 < e) ? (int)(pw.z >> 15) : c0;
            int c3 = (j + 3 < e) ? (int)(pw.w >> 15) : c0;
            uint4 q0 = ((const uint4*)(fin + ((long)c0 << 6)))[h];
            uint4 q1 = ((const uint4*)(fin + ((long)c1 << 6)))[h];
            uint4 q2 = ((const uint4*)(fin + ((long)c2 << 6)))[h];
            uint4 q3 = ((const uint4*)(fin + ((long)c3 << 6)))[h];
            half2_t w0 = dup_lo16(pw.x << 1);
            half2_t w1 = (j + 1 < e) ? dup_lo16(pw.y << 1) : (half2_t)0;
            half2_t w2 = (j + 2 < e) ? dup_lo16(pw.z << 1) : (half2_t)0;
            half2_t w3 = (j + 3 < e) ? dup_lo16(pw.w << 1) : (half2_t)0;
            a2[0] += w0 * __builtin_bit_cast(half2_t, q0.x);
            a2[1] += w0 * __builtin_bit_cast(half2_t, q0.y);
            a2[2] += w0 * __builtin_bit_cast(half2_t, q0.z);
            a2[3] += w0 * __builtin_bit_cast(half2_t, q0.w);
            a2[4] += w1 * __builtin_bit_cast(half2_t, q1.x);
            a2[5] += w1 * __builtin_bit_cast(half2_t, q1.y);
            a2[6] += w1 * __builtin_bit_cast(half2_t, q1.z);
            a2[7] += w1 * __builtin_bit_cast(half2_t, q1.w);
            a2[0] += w2 * __builtin_bit_cast(half2_t, q2.x);
            a2[1] += w2 * __builtin_bit_cast(half2_t, q2.y);
            a2[2] += w2 * __builtin_bit_cast(half2_t, q2.z);
            a2[3] += w2 * __builtin_bit_cast(half2_t, q2.w);
            a2[4] += w3 * __builtin_bit_cast(half2_t, q3.x);
            a2[5] += w3 * __builtin_bit_cast(half2_t, q3.y);
            a2[6] += w3 * __builtin_bit_cast(half2_t, q3.z);
            a2[7] += w3 * __builtin_bit_cast(half2_t, q3.w);
        }
    }

    // reduce slot partials across lane groups; lanes g==0 scale by inv_c and write
    #pragma unroll
    for (int k = 0; k < 4; k++) a2[k] += a2[k + 4];
    #pragma unroll
    for (int k = 0; k < 4; k++) {
        a2[k] += h2_shfl_xor(a2[k], 8);
        a2[k] += h2_shfl_xor(a2[k], 16);
        a2[k] += h2_shfl_xor(a2[k], 32);
    }
    if (g == 0) {
        half2_t ich = __builtin_bit_cast(half2_t, pk_f16x2(ic, ic));
        uint4 o;
        o.x = __builtin_bit_cast(unsigned int, a2[0] * ich);
        o.y = __builtin_bit_cast(unsigned int, a2[1] * ich);
        o.z = __builtin_bit_cast(unsigned int, a2[2] * ich);
        o.w = __builtin_bit_cast(unsigned int, a2[3] * ich);
        ((uint4*)(fout + ((long)wid << 6)))[h] = o;
    }
}

// ---- loss: reconstruct rep rows on the fly (f32 norms, layer-0 from f32 nf) ----
// stored_l = inv_c * x_l (row-uniform positive scale) -> x_l/||x_l|| == stored/||stored||
__device__ inline float rep_at(const float* __restrict__ nf,
                               const unsigned short* __restrict__ f1,
                               const unsigned short* __restrict__ f2,
                               const unsigned short* __restrict__ f3,
                               int id, int lane) {
    long off = (long)id * DDIM + lane;
    float r  = nf[off];
    float v1 = (float)__builtin_bit_cast(_Float16, f1[off]);
    float v2 = (float)__builtin_bit_cast(_Float16, f2[off]);
    float v3 = (float)__builtin_bit_cast(_Float16, f3[off]);
    float s1 = v1 * v1, s2 = v2 * v2, s3 = v3 * v3;
    #pragma unroll
    for (int o = 1; o < 64; o <<= 1) {
        s1 += __shfl_xor(s1, o);
        s2 += __shfl_xor(s2, o);
        s3 += __shfl_xor(s3, o);
    }
    r += v1 / fmaxf(sqrtf(s1), 1e-12f);
    r += v2 / fmaxf(sqrtf(s2), 1e-12f);
    r += v3 / fmaxf(sqrtf(s3), 1e-12f);
    return r;
}

__global__ void loss_terms_kernel(const float* __restrict__ nf,
                                  const unsigned short* __restrict__ f1,
                                  const unsigned short* __restrict__ f2,
                                  const unsigned short* __restrict__ f3,
                                  const int* __restrict__ a_id, const int* __restrict__ p_id,
                                  const int* __restrict__ n_id,
                                  float* __restrict__ terms, int B) {
    long gid = (long)blockIdx.x * blockDim.x + threadIdx.x;
    int b = (int)(gid >> 6);
    int lane = threadIdx.x & 63;
    if (b < B) {
        float ra = rep_at(nf, f1, f2, f3, a_id[b], lane);
        float rp = rep_at(nf, f1, f2, f3, p_id[b], lane);
        float rn = rep_at(nf, f1, f2, f3, n_id[b], lane);
        float dp = ra * rp, dn = ra * rn;
        #pragma unroll
        for (int off = 1; off < 64; off <<= 1) { dp += __shfl_xor(dp, off); dn += __shfl_xor(dn, off); }
        if (lane == 0) {
            float x = (dp - dn) * 0.0625f;   // node_rep = rep/4 -> preds scale 1/16
            terms[b] = fmaxf(-x, 0.0f) + log1pf(expf(-fabsf(x)));
        }
    }
}

__global__ void reduce_kernel(const float* __restrict__ terms, float* __restrict__ out, int B) {
    __shared__ float sm[256];
    float s = 0.0f;
    for (int i = threadIdx.x; i < B; i += 256) s += terms[i];
    sm[threadIdx.x] = s;
    __syncthreads();
    for (int stride = 128; stride > 0; stride >>= 1) {
        if (threadIdx.x < stride) sm[threadIdx.x] += sm[threadIdx.x + stride];
        __syncthreads();
    }
    if (threadIdx.x == 0) out[0] = sm[0] / (float)B;
}

extern "C" void kernel_launch(void* const* d_in, const int* in_sizes, int n_in,
                              void* d_out, int out_size, void* d_ws, size_t ws_size,
                              hipStream_t stream) {
    const float* nf    = (const float*)d_in[0];
    const int*   erow  = (const int*)d_in[1];
    const int*   ecol  = (const int*)d_in[2];
    const float* evals = (const float*)d_in[3];
    const int*   a_id  = (const int*)d_in[4];
    const int*   p_id  = (const int*)d_in[5];
    const int*   n_id  = (const int*)d_in[6];

    int N = in_sizes[0] / DDIM;
    int E = in_sizes[1];
    int B = in_sizes[4];
    int NB = (N + BUCKET - 1) / BUCKET;
    int chunk = (((E + NBLK - 1) / NBLK) + 3) & ~3;   // multiple of 4 -> aligned quad loads
    int Npad = NB * BUCKET;

    // bucket capacity: mean + ~8.3% (15 sigma) + 5120 (mod-4 rounding pad 3072 + guard)
    long capl = ((long)E * BUCKET) / N;
    int cap = (int)(capl + capl / 12 + 5120);
    cap = (cap + 63) & ~63;

    size_t regionA = (size_t)cap * NB * 8;            // br (8 B), later fb0+fb1
    size_t regionB = (size_t)cap * NB * 4;            // bc (4 B), later cw (4 B)
    size_t featB16 = (size_t)N * DDIM * 2;
    if (regionA < 2 * featB16) regionA = 2 * featB16;

    char* w = (char*)d_ws;
    ull*  br     = (ull*)w;
    char* regAp  = w;                 w += regionA;
    unsigned int* bc = (unsigned int*)w;
    unsigned int* cw = (unsigned int*)w;  w += regionB + 256;  // +256: spmm quad tail overread pad
    unsigned short* fb2 = (unsigned short*)w;  w += featB16;   // layer-2 output
    float* inv_c = (float*)w;         w += (size_t)Npad * 4;
    int2* rse    = (int2*)w;          w += (size_t)N * 8;
    int* gfill_r = (int*)w;           w += (size_t)NB * 16 * 4;
    int* gfill_c = (int*)w;           w += (size_t)NB * 16 * 4;
    float* terms = (float*)w;         w += (size_t)B * 4;

    unsigned short* fb0 = (unsigned short*)regAp;             // aliases br (dead after fused_cp)
    unsigned short* fb1 = (unsigned short*)(regAp + featB16);

    init_fill_kernel<<<1, 128, 0, stream>>>(gfill_r, gfill_c, NB, cap);
    binning_kernel<<<NBLK, TPB_BIN, 0, stream>>>(erow, ecol, evals, gfill_r, gfill_c,
                                                 br, bc, E, NB, chunk);
    fused_cp_kernel<<<NB * 4, BUCKET, 0, stream>>>(br, bc, gfill_r, gfill_c,
                                                   rse, inv_c, cw, N, cap);

    long n4 = (long)N * DDIM / 4;
    cvt_kernel<<<(unsigned)((n4 + 255) / 256), 256, 0, stream>>>(nf, inv_c, (unsigned int*)fb0, n4);

    unsigned spmmGrid = (unsigned)((N + 3) / 4);   // 4 waves (rows) per 256-thread block
    // layers: fb0 -> fb1 -> fb2 -> fb0 (fb0 slot reused; loss reads f32 nf for layer 0)
    spmm_f16_kernel<<<spmmGrid, 256, 0, stream>>>(rse, cw, inv_c, fb0, fb1, N);
    spmm_f16_kernel<<<spmmGrid, 256, 0, stream>>>(rse, cw, inv_c, fb1, fb2, N);
    spmm_f16_kernel<<<spmmGrid, 256, 0, stream>>>(rse, cw, inv_c, fb2, fb0, N);

    loss_terms_kernel<<<(unsigned)(((long)B * 64 + 255) / 256), 256, 0, stream>>>(
        nf, fb1, fb2, fb0, a_id, p_id, n_id, terms, B);
    reduce_kernel<<<1, 256, 0, stream>>>(terms, (float*)d_out, B);
}